// Round 5
// baseline (1589.580 us; speedup 1.0000x reference)
//
#include <hip/hip_runtime.h>
#include <math.h>

#define B_    32
#define T_    512
#define WDIM_ 300
#define H_    256
#define G4_   1024            // 4*H
#define M_    (B_ * T_)       // 16384

// persistent-LSTM geometry: team = 8 WGs covering one (dir, batch-pair)
#define NCG   8               // col groups per team (32 d's each)
#define NWG   256             // 2 dirs * 16 batch-pairs * NCG
#define THR   512
#define HXN   (2 * 2 * B_ * H_)   // packets: [buf][dir][32][256]

// ---------------------------------------------------------------------------
// Kernel 1: z = relu(emb[x] @ W_in + b_in)   [16384,300]@[300,256]
// ---------------------------------------------------------------------------
__global__ __launch_bounds__(256)
void k_embed_proj(const float* __restrict__ emb, const float* __restrict__ Win,
                  const float* __restrict__ bin, const int* __restrict__ x,
                  float* __restrict__ z)
{
    __shared__ float Ash[16][132];
    __shared__ float Bsh[16][132];
    __shared__ int   rows[128];

    const int tid = threadIdx.x;
    const int tx = tid & 15, ty = tid >> 4;
    const int rm = blockIdx.y * 128;
    const int cn = blockIdx.x * 128;

    if (tid < 128) rows[tid] = x[rm + tid];
    __syncthreads();

    float acc[8][8];
#pragma unroll
    for (int i = 0; i < 8; ++i)
#pragma unroll
        for (int j = 0; j < 8; ++j) acc[i][j] = 0.f;

    for (int kc = 0; kc < 19; ++kc) {
        const int k0 = kc * 16;
#pragma unroll
        for (int e = 0; e < 8; ++e) {
            const int idx = e * 256 + tid;
            const int r = idx >> 4, kk = idx & 15;
            const int k = k0 + kk;
            const int v = rows[r];
            Ash[kk][r] = (k < WDIM_) ? emb[(size_t)v * WDIM_ + k] : 0.f;
        }
#pragma unroll
        for (int e = 0; e < 8; ++e) {
            const int idx = e * 256 + tid;
            const int kk = idx >> 7, n = idx & 127;
            const int k = k0 + kk;
            Bsh[kk][n] = (k < WDIM_) ? Win[(size_t)k * H_ + cn + n] : 0.f;
        }
        __syncthreads();
#pragma unroll
        for (int kk = 0; kk < 16; ++kk) {
            float a[8], bb[8];
#pragma unroll
            for (int i = 0; i < 8; ++i) a[i] = Ash[kk][ty * 8 + i];
#pragma unroll
            for (int j = 0; j < 8; ++j) bb[j] = Bsh[kk][tx * 8 + j];
#pragma unroll
            for (int i = 0; i < 8; ++i)
#pragma unroll
                for (int j = 0; j < 8; ++j) acc[i][j] += a[i] * bb[j];
        }
        __syncthreads();
    }

#pragma unroll
    for (int i = 0; i < 8; ++i) {
        const int row = rm + ty * 8 + i;
#pragma unroll
        for (int j = 0; j < 8; ++j) {
            const int col = cn + tx * 8 + j;
            z[(size_t)row * H_ + col] = fmaxf(acc[i][j] + bin[col], 0.f);
        }
    }
}

// ---------------------------------------------------------------------------
// Kernel 2: P_d = z @ Wih_d + bl_d  (both directions via blockIdx.z)
// ---------------------------------------------------------------------------
__global__ __launch_bounds__(256)
void k_in_proj(const float* __restrict__ z,
               const float* __restrict__ Wf, const float* __restrict__ blf,
               const float* __restrict__ Wb, const float* __restrict__ blb,
               float* __restrict__ Pf, float* __restrict__ Pb)
{
    const float* W  = blockIdx.z ? Wb  : Wf;
    const float* bl = blockIdx.z ? blb : blf;
    float*       P  = blockIdx.z ? Pb  : Pf;

    __shared__ float Ash[16][132];
    __shared__ float Bsh[16][132];

    const int tid = threadIdx.x;
    const int tx = tid & 15, ty = tid >> 4;
    const int rm = blockIdx.y * 128;
    const int cn = blockIdx.x * 128;

    float acc[8][8];
#pragma unroll
    for (int i = 0; i < 8; ++i)
#pragma unroll
        for (int j = 0; j < 8; ++j) acc[i][j] = 0.f;

    for (int kc = 0; kc < 16; ++kc) {
        const int k0 = kc * 16;
#pragma unroll
        for (int e = 0; e < 8; ++e) {
            const int idx = e * 256 + tid;
            const int r = idx >> 4, kk = idx & 15;
            Ash[kk][r] = z[(size_t)(rm + r) * H_ + k0 + kk];
        }
#pragma unroll
        for (int e = 0; e < 8; ++e) {
            const int idx = e * 256 + tid;
            const int kk = idx >> 7, n = idx & 127;
            Bsh[kk][n] = W[(size_t)(k0 + kk) * G4_ + cn + n];
        }
        __syncthreads();
#pragma unroll
        for (int kk = 0; kk < 16; ++kk) {
            float a[8], bb[8];
#pragma unroll
            for (int i = 0; i < 8; ++i) a[i] = Ash[kk][ty * 8 + i];
#pragma unroll
            for (int j = 0; j < 8; ++j) bb[j] = Bsh[kk][tx * 8 + j];
#pragma unroll
            for (int i = 0; i < 8; ++i)
#pragma unroll
                for (int j = 0; j < 8; ++j) acc[i][j] += a[i] * bb[j];
        }
        __syncthreads();
    }

#pragma unroll
    for (int i = 0; i < 8; ++i) {
        const int row = rm + ty * 8 + i;
#pragma unroll
        for (int j = 0; j < 8; ++j) {
            const int col = cn + tx * 8 + j;
            P[(size_t)row * G4_ + col] = acc[i][j] + bl[col];
        }
    }
}

// ---------------------------------------------------------------------------
// Init: zero h packet buffers ({h=0, tag=0} == initial state)
// ---------------------------------------------------------------------------
__global__ void k_init(unsigned long long* __restrict__ hx)
{
    const int i = blockIdx.x * blockDim.x + threadIdx.x;
    if (i < HXN) hx[i] = 0ull;
}

// ---------------------------------------------------------------------------
// Kernel 3: persistent bidirectional LSTM recurrence, fence-free.
// WG = (dir, batch-pair bg, colgroup cg of 32 d's). Team = 8 colgroups.
// h published as {h,tag} 8-byte relaxed agent-scope atomic packets, double-
// buffered by step parity; readers poll tag>=s.
//
// v6: Whh slice STAGED IN LDS (128 KB, loaded once in a prologue), GEMV
// reads weights from LDS every step. Rationale: v1/v3/v5 all report
// VGPR_Count=56 -- the register allocator spills the 64-float slice to
// scratch no matter how it's expressed (arrays, per-elem asm pins, named
// scalars + single asm pin), so every step re-reads 256B/thread from
// scratch-through-L2: 128KB/CU/step -> ~2300 of the 4340 cyc/step (per-XCD
// L2 BW bound; invisible in FETCH_SIZE since scratch is L2-resident).
// LDS sidesteps regalloc: per-CU-private pipe, 128KB/step at ~128B/cy
// ~= 1024 cyc, overlappable across the 8 waves.
// Layout wlds[cl][k ^ ((cl&7)<<2)]: [cl][k] gives each thread a contiguous
// 256B row (16x ds_read_b128/step); the XOR spreads the stride-1KB lane
// pattern across all 32 banks (write and read use the SAME xor).
// GEMV arithmetic order bitwise-identical to the 913us version.
// ---------------------------------------------------------------------------
__global__ __launch_bounds__(THR, 2)
void k_lstm_persist(const float* __restrict__ Pf, const float* __restrict__ Pb,
                    const float* __restrict__ Whf, const float* __restrict__ Whb,
                    const int* __restrict__ lengths,
                    unsigned long long* __restrict__ hx,
                    float* __restrict__ pool)
{
    __shared__ float wlds[128 * 256];   // 128 KB: [cl][k^swz]
    __shared__ float h_sh[2][256];
    __shared__ float zp[4][2][128];     // [ksplit][row][local gate-col]

    const int tid = threadIdx.x;
    const int wg  = blockIdx.x;
    const int bg  = wg & 15;
    const int dir = (wg >> 4) & 1;
    const int cg  = wg >> 5;          // 0..7

    const float* P   = dir ? Pb  : Pf;
    const float* Whh = dir ? Whb : Whf;

    const int brow0 = bg * 2;
    const int len0 = lengths[brow0], len1 = lengths[brow0 + 1];
    const int tmax = max(len0, len1);

    // GEMV mapping: q = k-quarter, cl = local col in [0,128)
    const int q   = tid >> 7;
    const int cl  = tid & 127;
    const int g0  = cl >> 5;
    const int dd0 = cl & 31;
    const int gcol = g0 * 256 + cg * 32 + dd0;    // global column
    const int q64 = q * 64;

    // ---- prologue: stage this WG's Whh slice into LDS (transposed+swizzled)
    // element (k, c) -> wlds[c*256 + (k ^ ((c&7)<<2))]
    {
#pragma unroll
        for (int it = 0; it < 64; ++it) {
            const int idx = it * 512 + tid;       // 0..32767
            const int k  = idx >> 7;              // 0..255
            const int c  = idx & 127;             // 0..127
            const int gc = (c >> 5) * 256 + cg * 32 + (c & 31);
            wlds[c * 256 + (k ^ ((c & 7) << 2))] =
                Whh[(size_t)k * G4_ + gc];
        }
    }

    // gate mapping (tid < 64): row gr, local hidden index gd
    const int gr    = tid >> 5;
    const int gd    = tid & 31;
    const int gbrow = brow0 + gr;
    const int glen  = gr ? len1 : len0;
    float cst = 0.f, hreg = 0.f, pacc = 0.f;

    // h-packet loader mapping (all 512 threads): row lrow, index ld
    const int lrow = tid >> 8;
    const int ld   = tid & 255;
    unsigned long long* slotR = hx + ((size_t)dir * 32 + brow0 + lrow) * 256 + ld;
    unsigned long long* slotW = hx + ((size_t)dir * 32 + gbrow) * 256 + cg * 32 + gd;
    const size_t bufStride = (size_t)2 * B_ * H_;   // packets per parity

    // per-thread weight row base (float index) and swizzle constant
    const int wb = cl * 256 + q64;
    const int sw = (cl & 7) << 2;

    __syncthreads();   // wlds ready before first GEMV

    for (int s = 0; s < tmax; ++s) {
        const int tt = dir ? (tmax - 1 - s) : s;

        // prefetch input projection for this step (independent of the poll)
        float pv0 = 0.f, pv1 = 0.f, pv2 = 0.f, pv3 = 0.f;
        if (tid < 64) {
            const float* pr = P + (size_t)(gbrow * T_ + tt) * G4_ + cg * 32 + gd;
            pv0 = pr[0]; pv1 = pr[256]; pv2 = pr[512]; pv3 = pr[768];
        }

        // poll h_{s-1} packets (tag s) and stage into LDS
        {
            const unsigned long long* sp = slotR + (size_t)(s & 1) * bufStride;
            unsigned long long pk = __hip_atomic_load(sp, __ATOMIC_RELAXED,
                                                      __HIP_MEMORY_SCOPE_AGENT);
            while ((unsigned)(pk >> 32) < (unsigned)s) {
                __builtin_amdgcn_s_sleep(1);
                pk = __hip_atomic_load(sp, __ATOMIC_RELAXED,
                                       __HIP_MEMORY_SCOPE_AGENT);
            }
            h_sh[lrow][ld] = __uint_as_float((unsigned)pk);
        }
        __syncthreads();

        // GEMV: 2 rows x 1 col over k in [64q, 64q+64); weights from LDS
        {
            const float* h0 = &h_sh[0][q64];
            const float* h1 = &h_sh[1][q64];
            float a0 = 0.f, a1 = 0.f;
#define GQ(J) { \
            const float4 wq  = *(const float4*)&wlds[wb + ((4*(J)) ^ sw)]; \
            const float4 hv0 = *(const float4*)(h0 + 4 * (J)); \
            const float4 hv1 = *(const float4*)(h1 + 4 * (J)); \
            a0 += hv0.x * wq.x; a1 += hv1.x * wq.x; \
            a0 += hv0.y * wq.y; a1 += hv1.y * wq.y; \
            a0 += hv0.z * wq.z; a1 += hv1.z * wq.z; \
            a0 += hv0.w * wq.w; a1 += hv1.w * wq.w; }
            GQ(0)  GQ(1)  GQ(2)  GQ(3)
            GQ(4)  GQ(5)  GQ(6)  GQ(7)
            GQ(8)  GQ(9)  GQ(10) GQ(11)
            GQ(12) GQ(13) GQ(14) GQ(15)
#undef GQ
            zp[q][0][cl] = a0;
            zp[q][1][cl] = a1;
        }
        __syncthreads();

        // gates + state update + h-packet publish (tag s+1, parity (s+1)&1)
        if (tid < 64) {
            float zi = pv0 + zp[0][gr][gd]      + zp[1][gr][gd]      + zp[2][gr][gd]      + zp[3][gr][gd];
            float zf = pv1 + zp[0][gr][32 + gd] + zp[1][gr][32 + gd] + zp[2][gr][32 + gd] + zp[3][gr][32 + gd];
            float zg = pv2 + zp[0][gr][64 + gd] + zp[1][gr][64 + gd] + zp[2][gr][64 + gd] + zp[3][gr][64 + gd];
            float zo = pv3 + zp[0][gr][96 + gd] + zp[1][gr][96 + gd] + zp[2][gr][96 + gd] + zp[3][gr][96 + gd];
            const float ig = 1.f / (1.f + expf(-zi));
            const float fg = 1.f / (1.f + expf(-zf));
            const float gg = tanhf(zg);
            const float og = 1.f / (1.f + expf(-zo));
            const float cn = fg * cst + ig * gg;
            const float hn = og * tanhf(cn);
            if (tt < glen) { cst = cn; hreg = hn; pacc += hn; }
            const unsigned long long opk =
                ((unsigned long long)(unsigned)(s + 1) << 32) |
                (unsigned long long)__float_as_uint(hreg);
            __hip_atomic_store(slotW + (size_t)((s + 1) & 1) * bufStride, opk,
                               __ATOMIC_RELAXED, __HIP_MEMORY_SCOPE_AGENT);
        }
        // no trailing barrier: zp of step s+1 is written only after the next
        // post-poll __syncthreads, which gate threads reach after this block.
    }

    if (tid < 64)
        pool[gbrow * 512 + dir * 256 + cg * 32 + gd] = pacc / (float)glen;
}

// ---------------------------------------------------------------------------
// Kernel 4: fc_hidden = relu(pool @ Wfc + bfc); out = fc_hidden @ Wout + bout
// ---------------------------------------------------------------------------
__global__ __launch_bounds__(256)
void k_fc(const float* __restrict__ pool, const float* __restrict__ Wfc,
          const float* __restrict__ bfc, const float* __restrict__ Wout,
          const float* __restrict__ bout, float* __restrict__ out)
{
    __shared__ float p_sh[512];
    __shared__ float red[8];

    const int tid = threadIdx.x;
    const int b   = blockIdx.x;

    p_sh[tid]       = pool[b * 512 + tid];
    p_sh[256 + tid] = pool[b * 512 + 256 + tid];
    __syncthreads();

    float acc = bfc[tid];
#pragma unroll 8
    for (int k = 0; k < 512; ++k)
        acc += p_sh[k] * Wfc[(size_t)k * H_ + tid];
    const float fh = fmaxf(acc, 0.f);

    float p0 = fh * Wout[tid * 2 + 0];
    float p1 = fh * Wout[tid * 2 + 1];
#pragma unroll
    for (int off = 32; off > 0; off >>= 1) {
        p0 += __shfl_down(p0, off);
        p1 += __shfl_down(p1, off);
    }
    const int wave = tid >> 6;
    if ((tid & 63) == 0) { red[wave * 2] = p0; red[wave * 2 + 1] = p1; }
    __syncthreads();
    if (tid == 0) {
        out[b * 2 + 0] = red[0] + red[2] + red[4] + red[6] + bout[0];
        out[b * 2 + 1] = red[1] + red[3] + red[5] + red[7] + bout[1];
    }
}

__global__ void k_sentinel(float* out, int n)
{
    const int i = blockIdx.x * blockDim.x + threadIdx.x;
    if (i < n) out[i] = 1.0e9f;
}

extern "C" void kernel_launch(void* const* d_in, const int* in_sizes, int n_in,
                              void* d_out, int out_size, void* d_ws, size_t ws_size,
                              hipStream_t stream)
{
    const float* emb  = (const float*)d_in[0];
    const float* Win  = (const float*)d_in[1];
    const float* bin  = (const float*)d_in[2];
    const float* Wihf = (const float*)d_in[3];
    const float* Whhf = (const float*)d_in[4];
    const float* blf  = (const float*)d_in[5];
    const float* Wihb = (const float*)d_in[6];
    const float* Whhb = (const float*)d_in[7];
    const float* blb  = (const float*)d_in[8];
    const float* Wfc  = (const float*)d_in[9];
    const float* bfc  = (const float*)d_in[10];
    const float* Wout = (const float*)d_in[11];
    const float* bout = (const float*)d_in[12];
    const int*   x    = (const int*)d_in[13];
    const int*   lens = (const int*)d_in[15];
    float*       out  = (float*)d_out;

    const size_t need = ((size_t)M_ * H_ + 2 * (size_t)M_ * G4_) * sizeof(float);
    if (ws_size < need) {
        hipLaunchKernelGGL(k_sentinel, dim3(1), dim3(64), 0, stream, out, out_size);
        return;
    }

    float* z  = (float*)d_ws;                    // [16384,256] (dead after k2)
    float* Pf = z + (size_t)M_ * H_;             // [16384,1024]
    float* Pb = Pf + (size_t)M_ * G4_;           // [16384,1024]

    // overlay inside z region (init runs after k2 has consumed z)
    unsigned long long* hx   = (unsigned long long*)d_ws;        // packets
    float*              pool = (float*)(hx + HXN);               // [32][512]

    hipLaunchKernelGGL(k_embed_proj, dim3(2, 128), dim3(256), 0, stream,
                       emb, Win, bin, x, z);
    hipLaunchKernelGGL(k_in_proj, dim3(8, 128, 2), dim3(256), 0, stream,
                       z, Wihf, blf, Wihb, blb, Pf, Pb);
    hipLaunchKernelGGL(k_init, dim3(128), dim3(256), 0, stream, hx);
    hipLaunchKernelGGL(k_lstm_persist, dim3(NWG), dim3(THR), 0, stream,
                       Pf, Pb, Whhf, Whhb, lens, hx, pool);
    hipLaunchKernelGGL(k_fc, dim3(32), dim3(256), 0, stream,
                       pool, Wfc, bfc, Wout, bout, out);
}

// Round 7
// 1570.107 us; speedup vs baseline: 1.0124x; 1.0124x over previous
//
#include <hip/hip_runtime.h>
#include <math.h>

#define B_    32
#define T_    512
#define WDIM_ 300
#define H_    256
#define G4_   1024            // 4*H
#define M_    (B_ * T_)       // 16384

// persistent-LSTM geometry: team = 8 WGs covering one (dir, batch-pair)
#define NCG   8               // col groups per team (32 d's each)
#define NWG   256             // 2 dirs * 16 batch-pairs * NCG
#define THR   512
#define HXN   (2 * 2 * B_ * H_)   // packets: [buf][dir][32][256]

// ---------------------------------------------------------------------------
// Kernel 1: z = relu(emb[x] @ W_in + b_in)   [16384,300]@[300,256]
// ---------------------------------------------------------------------------
__global__ __launch_bounds__(256)
void k_embed_proj(const float* __restrict__ emb, const float* __restrict__ Win,
                  const float* __restrict__ bin, const int* __restrict__ x,
                  float* __restrict__ z)
{
    __shared__ float Ash[16][132];
    __shared__ float Bsh[16][132];
    __shared__ int   rows[128];

    const int tid = threadIdx.x;
    const int tx = tid & 15, ty = tid >> 4;
    const int rm = blockIdx.y * 128;
    const int cn = blockIdx.x * 128;

    if (tid < 128) rows[tid] = x[rm + tid];
    __syncthreads();

    float acc[8][8];
#pragma unroll
    for (int i = 0; i < 8; ++i)
#pragma unroll
        for (int j = 0; j < 8; ++j) acc[i][j] = 0.f;

    for (int kc = 0; kc < 19; ++kc) {
        const int k0 = kc * 16;
#pragma unroll
        for (int e = 0; e < 8; ++e) {
            const int idx = e * 256 + tid;
            const int r = idx >> 4, kk = idx & 15;
            const int k = k0 + kk;
            const int v = rows[r];
            Ash[kk][r] = (k < WDIM_) ? emb[(size_t)v * WDIM_ + k] : 0.f;
        }
#pragma unroll
        for (int e = 0; e < 8; ++e) {
            const int idx = e * 256 + tid;
            const int kk = idx >> 7, n = idx & 127;
            const int k = k0 + kk;
            Bsh[kk][n] = (k < WDIM_) ? Win[(size_t)k * H_ + cn + n] : 0.f;
        }
        __syncthreads();
#pragma unroll
        for (int kk = 0; kk < 16; ++kk) {
            float a[8], bb[8];
#pragma unroll
            for (int i = 0; i < 8; ++i) a[i] = Ash[kk][ty * 8 + i];
#pragma unroll
            for (int j = 0; j < 8; ++j) bb[j] = Bsh[kk][tx * 8 + j];
#pragma unroll
            for (int i = 0; i < 8; ++i)
#pragma unroll
                for (int j = 0; j < 8; ++j) acc[i][j] += a[i] * bb[j];
        }
        __syncthreads();
    }

#pragma unroll
    for (int i = 0; i < 8; ++i) {
        const int row = rm + ty * 8 + i;
#pragma unroll
        for (int j = 0; j < 8; ++j) {
            const int col = cn + tx * 8 + j;
            z[(size_t)row * H_ + col] = fmaxf(acc[i][j] + bin[col], 0.f);
        }
    }
}

// ---------------------------------------------------------------------------
// Kernel 2: P_d = z @ Wih_d + bl_d  (both directions via blockIdx.z)
// ---------------------------------------------------------------------------
__global__ __launch_bounds__(256)
void k_in_proj(const float* __restrict__ z,
               const float* __restrict__ Wf, const float* __restrict__ blf,
               const float* __restrict__ Wb, const float* __restrict__ blb,
               float* __restrict__ Pf, float* __restrict__ Pb)
{
    const float* W  = blockIdx.z ? Wb  : Wf;
    const float* bl = blockIdx.z ? blb : blf;
    float*       P  = blockIdx.z ? Pb  : Pf;

    __shared__ float Ash[16][132];
    __shared__ float Bsh[16][132];

    const int tid = threadIdx.x;
    const int tx = tid & 15, ty = tid >> 4;
    const int rm = blockIdx.y * 128;
    const int cn = blockIdx.x * 128;

    float acc[8][8];
#pragma unroll
    for (int i = 0; i < 8; ++i)
#pragma unroll
        for (int j = 0; j < 8; ++j) acc[i][j] = 0.f;

    for (int kc = 0; kc < 16; ++kc) {
        const int k0 = kc * 16;
#pragma unroll
        for (int e = 0; e < 8; ++e) {
            const int idx = e * 256 + tid;
            const int r = idx >> 4, kk = idx & 15;
            Ash[kk][r] = z[(size_t)(rm + r) * H_ + k0 + kk];
        }
#pragma unroll
        for (int e = 0; e < 8; ++e) {
            const int idx = e * 256 + tid;
            const int kk = idx >> 7, n = idx & 127;
            Bsh[kk][n] = W[(size_t)(k0 + kk) * G4_ + cn + n];
        }
        __syncthreads();
#pragma unroll
        for (int kk = 0; kk < 16; ++kk) {
            float a[8], bb[8];
#pragma unroll
            for (int i = 0; i < 8; ++i) a[i] = Ash[kk][ty * 8 + i];
#pragma unroll
            for (int j = 0; j < 8; ++j) bb[j] = Bsh[kk][tx * 8 + j];
#pragma unroll
            for (int i = 0; i < 8; ++i)
#pragma unroll
                for (int j = 0; j < 8; ++j) acc[i][j] += a[i] * bb[j];
        }
        __syncthreads();
    }

#pragma unroll
    for (int i = 0; i < 8; ++i) {
        const int row = rm + ty * 8 + i;
#pragma unroll
        for (int j = 0; j < 8; ++j) {
            const int col = cn + tx * 8 + j;
            P[(size_t)row * G4_ + col] = acc[i][j] + bl[col];
        }
    }
}

// ---------------------------------------------------------------------------
// Init: zero h packet buffers ({h=0, tag=0} == initial state)
// ---------------------------------------------------------------------------
__global__ void k_init(unsigned long long* __restrict__ hx)
{
    const int i = blockIdx.x * blockDim.x + threadIdx.x;
    if (i < HXN) hx[i] = 0ull;
}

// ---------------------------------------------------------------------------
// Kernel 3: persistent bidirectional LSTM recurrence, fence-free.
// WG = (dir, batch-pair bg, colgroup cg of 32 d's). Team = 8 colgroups.
// h published as {h,tag} 8-byte relaxed agent-scope atomic packets, double-
// buffered by step parity; readers poll tag>=s.
//
// v7 (resubmitted unchanged -- round 6 failed on infra, not the kernel):
// Whh slice in LDS with CONFLICT-FREE layout wlds[k][c] (k-major).
// v6's [cl][k]+XOR read had bank = ((4J)^((cl&7)<<2)) -- only 8 distinct
// bank-quads for 64 lanes = 8-way conflict (5.6e7 SQ_LDS_BANK_CONFLICT,
// +235us). With [k][c], the weight read is scalar ds_read_b32 at
// (q64+4J+j)*128 + cl: bank = cl&31, lanes have consecutive cl -> 2
// lanes/bank = free (m136). Per-thread: one base VGPR (&wlds[cl+q64*128])
// + 64 compile-time immediate offsets (max 32256 B < 65536 B field).
// Staging: writes stride-1 (conflict-free), reads coalesced. LDS/CU/step:
// ~1024cy weights + ~400cy h-broadcasts, pipelined across 8 waves --
// replaces v1's ~2300cy of per-XCD L2 weight refetch (compiler remat/spill
// of the 64-float slice, proven unavoidable at source level in v3/v4/v5).
// GEMV arithmetic order bitwise-identical to v1 (913us, absmax 0).
// ---------------------------------------------------------------------------
__global__ __launch_bounds__(THR, 2)
void k_lstm_persist(const float* __restrict__ Pf, const float* __restrict__ Pb,
                    const float* __restrict__ Whf, const float* __restrict__ Whb,
                    const int* __restrict__ lengths,
                    unsigned long long* __restrict__ hx,
                    float* __restrict__ pool)
{
    __shared__ float wlds[256 * 128];   // 128 KB: [k][c]
    __shared__ float h_sh[2][256];
    __shared__ float zp[4][2][128];     // [ksplit][row][local gate-col]

    const int tid = threadIdx.x;
    const int wg  = blockIdx.x;
    const int bg  = wg & 15;
    const int dir = (wg >> 4) & 1;
    const int cg  = wg >> 5;          // 0..7

    const float* P   = dir ? Pb  : Pf;
    const float* Whh = dir ? Whb : Whf;

    const int brow0 = bg * 2;
    const int len0 = lengths[brow0], len1 = lengths[brow0 + 1];
    const int tmax = max(len0, len1);

    // GEMV mapping: q = k-quarter, cl = local col in [0,128)
    const int q   = tid >> 7;
    const int cl  = tid & 127;
    const int g0  = cl >> 5;
    const int dd0 = cl & 31;
    const int gcol = g0 * 256 + cg * 32 + dd0;    // global column
    const int q64 = q * 64;

    // ---- prologue: stage this WG's Whh slice into LDS, k-major [k][c]
    // element (k, c) -> wlds[k*128 + c]; writes stride-1, reads coalesced
#pragma unroll 4
    for (int it = 0; it < 64; ++it) {
        const int idx = it * 512 + tid;       // 0..32767
        const int k  = idx >> 7;              // 0..255
        const int c  = idx & 127;             // 0..127
        const int gc = (c >> 5) * 256 + cg * 32 + (c & 31);
        wlds[k * 128 + c] = Whh[(size_t)k * G4_ + gc];
    }

    // gate mapping (tid < 64): row gr, local hidden index gd
    const int gr    = tid >> 5;
    const int gd    = tid & 31;
    const int gbrow = brow0 + gr;
    const int glen  = gr ? len1 : len0;
    float cst = 0.f, hreg = 0.f, pacc = 0.f;

    // h-packet loader mapping (all 512 threads): row lrow, index ld
    const int lrow = tid >> 8;
    const int ld   = tid & 255;
    unsigned long long* slotR = hx + ((size_t)dir * 32 + brow0 + lrow) * 256 + ld;
    unsigned long long* slotW = hx + ((size_t)dir * 32 + gbrow) * 256 + cg * 32 + gd;
    const size_t bufStride = (size_t)2 * B_ * H_;   // packets per parity

    // per-thread weight column base: wlds[q64*128 + cl], element (J,j) at
    // compile-time offset (4J+j)*128 floats (<= 32256 B immediate)
    const float* wcol = &wlds[q64 * 128 + cl];

    __syncthreads();   // wlds ready before first GEMV

    for (int s = 0; s < tmax; ++s) {
        const int tt = dir ? (tmax - 1 - s) : s;

        // prefetch input projection for this step (independent of the poll)
        float pv0 = 0.f, pv1 = 0.f, pv2 = 0.f, pv3 = 0.f;
        if (tid < 64) {
            const float* pr = P + (size_t)(gbrow * T_ + tt) * G4_ + cg * 32 + gd;
            pv0 = pr[0]; pv1 = pr[256]; pv2 = pr[512]; pv3 = pr[768];
        }

        // poll h_{s-1} packets (tag s) and stage into LDS
        {
            const unsigned long long* sp = slotR + (size_t)(s & 1) * bufStride;
            unsigned long long pk = __hip_atomic_load(sp, __ATOMIC_RELAXED,
                                                      __HIP_MEMORY_SCOPE_AGENT);
            while ((unsigned)(pk >> 32) < (unsigned)s) {
                __builtin_amdgcn_s_sleep(1);
                pk = __hip_atomic_load(sp, __ATOMIC_RELAXED,
                                       __HIP_MEMORY_SCOPE_AGENT);
            }
            h_sh[lrow][ld] = __uint_as_float((unsigned)pk);
        }
        __syncthreads();

        // GEMV: 2 rows x 1 col over k in [64q, 64q+64); weights from LDS
        // (conflict-free scalar reads), h via wave-uniform broadcasts
        {
            const float* h0 = &h_sh[0][q64];
            const float* h1 = &h_sh[1][q64];
            float a0 = 0.f, a1 = 0.f;
#define GQ(J) { \
            const float4 hv0 = *(const float4*)(h0 + 4 * (J)); \
            const float4 hv1 = *(const float4*)(h1 + 4 * (J)); \
            const float w0 = wcol[(4*(J)+0)*128]; \
            const float w1 = wcol[(4*(J)+1)*128]; \
            const float w2 = wcol[(4*(J)+2)*128]; \
            const float w3 = wcol[(4*(J)+3)*128]; \
            a0 += hv0.x * w0; a1 += hv1.x * w0; \
            a0 += hv0.y * w1; a1 += hv1.y * w1; \
            a0 += hv0.z * w2; a1 += hv1.z * w2; \
            a0 += hv0.w * w3; a1 += hv1.w * w3; }
            GQ(0)  GQ(1)  GQ(2)  GQ(3)
            GQ(4)  GQ(5)  GQ(6)  GQ(7)
            GQ(8)  GQ(9)  GQ(10) GQ(11)
            GQ(12) GQ(13) GQ(14) GQ(15)
#undef GQ
            zp[q][0][cl] = a0;
            zp[q][1][cl] = a1;
        }
        __syncthreads();

        // gates + state update + h-packet publish (tag s+1, parity (s+1)&1)
        if (tid < 64) {
            float zi = pv0 + zp[0][gr][gd]      + zp[1][gr][gd]      + zp[2][gr][gd]      + zp[3][gr][gd];
            float zf = pv1 + zp[0][gr][32 + gd] + zp[1][gr][32 + gd] + zp[2][gr][32 + gd] + zp[3][gr][32 + gd];
            float zg = pv2 + zp[0][gr][64 + gd] + zp[1][gr][64 + gd] + zp[2][gr][64 + gd] + zp[3][gr][64 + gd];
            float zo = pv3 + zp[0][gr][96 + gd] + zp[1][gr][96 + gd] + zp[2][gr][96 + gd] + zp[3][gr][96 + gd];
            const float ig = 1.f / (1.f + expf(-zi));
            const float fg = 1.f / (1.f + expf(-zf));
            const float gg = tanhf(zg);
            const float og = 1.f / (1.f + expf(-zo));
            const float cn = fg * cst + ig * gg;
            const float hn = og * tanhf(cn);
            if (tt < glen) { cst = cn; hreg = hn; pacc += hn; }
            const unsigned long long opk =
                ((unsigned long long)(unsigned)(s + 1) << 32) |
                (unsigned long long)__float_as_uint(hreg);
            __hip_atomic_store(slotW + (size_t)((s + 1) & 1) * bufStride, opk,
                               __ATOMIC_RELAXED, __HIP_MEMORY_SCOPE_AGENT);
        }
        // no trailing barrier: zp of step s+1 is written only after the next
        // post-poll __syncthreads, which gate threads reach after this block.
    }

    if (tid < 64)
        pool[gbrow * 512 + dir * 256 + cg * 32 + gd] = pacc / (float)glen;
}

// ---------------------------------------------------------------------------
// Kernel 4: fc_hidden = relu(pool @ Wfc + bfc); out = fc_hidden @ Wout + bout
// ---------------------------------------------------------------------------
__global__ __launch_bounds__(256)
void k_fc(const float* __restrict__ pool, const float* __restrict__ Wfc,
          const float* __restrict__ bfc, const float* __restrict__ Wout,
          const float* __restrict__ bout, float* __restrict__ out)
{
    __shared__ float p_sh[512];
    __shared__ float red[8];

    const int tid = threadIdx.x;
    const int b   = blockIdx.x;

    p_sh[tid]       = pool[b * 512 + tid];
    p_sh[256 + tid] = pool[b * 512 + 256 + tid];
    __syncthreads();

    float acc = bfc[tid];
#pragma unroll 8
    for (int k = 0; k < 512; ++k)
        acc += p_sh[k] * Wfc[(size_t)k * H_ + tid];
    const float fh = fmaxf(acc, 0.f);

    float p0 = fh * Wout[tid * 2 + 0];
    float p1 = fh * Wout[tid * 2 + 1];
#pragma unroll
    for (int off = 32; off > 0; off >>= 1) {
        p0 += __shfl_down(p0, off);
        p1 += __shfl_down(p1, off);
    }
    const int wave = tid >> 6;
    if ((tid & 63) == 0) { red[wave * 2] = p0; red[wave * 2 + 1] = p1; }
    __syncthreads();
    if (tid == 0) {
        out[b * 2 + 0] = red[0] + red[2] + red[4] + red[6] + bout[0];
        out[b * 2 + 1] = red[1] + red[3] + red[5] + red[7] + bout[1];
    }
}

__global__ void k_sentinel(float* out, int n)
{
    const int i = blockIdx.x * blockDim.x + threadIdx.x;
    if (i < n) out[i] = 1.0e9f;
}

extern "C" void kernel_launch(void* const* d_in, const int* in_sizes, int n_in,
                              void* d_out, int out_size, void* d_ws, size_t ws_size,
                              hipStream_t stream)
{
    const float* emb  = (const float*)d_in[0];
    const float* Win  = (const float*)d_in[1];
    const float* bin  = (const float*)d_in[2];
    const float* Wihf = (const float*)d_in[3];
    const float* Whhf = (const float*)d_in[4];
    const float* blf  = (const float*)d_in[5];
    const float* Wihb = (const float*)d_in[6];
    const float* Whhb = (const float*)d_in[7];
    const float* blb  = (const float*)d_in[8];
    const float* Wfc  = (const float*)d_in[9];
    const float* bfc  = (const float*)d_in[10];
    const float* Wout = (const float*)d_in[11];
    const float* bout = (const float*)d_in[12];
    const int*   x    = (const int*)d_in[13];
    const int*   lens = (const int*)d_in[15];
    float*       out  = (float*)d_out;

    const size_t need = ((size_t)M_ * H_ + 2 * (size_t)M_ * G4_) * sizeof(float);
    if (ws_size < need) {
        hipLaunchKernelGGL(k_sentinel, dim3(1), dim3(64), 0, stream, out, out_size);
        return;
    }

    float* z  = (float*)d_ws;                    // [16384,256] (dead after k2)
    float* Pf = z + (size_t)M_ * H_;             // [16384,1024]
    float* Pb = Pf + (size_t)M_ * G4_;           // [16384,1024]

    // overlay inside z region (init runs after k2 has consumed z)
    unsigned long long* hx   = (unsigned long long*)d_ws;        // packets
    float*              pool = (float*)(hx + HXN);               // [32][512]

    hipLaunchKernelGGL(k_embed_proj, dim3(2, 128), dim3(256), 0, stream,
                       emb, Win, bin, x, z);
    hipLaunchKernelGGL(k_in_proj, dim3(8, 128, 2), dim3(256), 0, stream,
                       z, Wihf, blf, Wihb, blb, Pf, Pb);
    hipLaunchKernelGGL(k_init, dim3(128), dim3(256), 0, stream, hx);
    hipLaunchKernelGGL(k_lstm_persist, dim3(NWG), dim3(THR), 0, stream,
                       Pf, Pb, Whhf, Whhb, lens, hx, pool);
    hipLaunchKernelGGL(k_fc, dim3(32), dim3(256), 0, stream,
                       pool, Wfc, bfc, Wout, bout, out);
}

// Round 8
// 1486.764 us; speedup vs baseline: 1.0692x; 1.0561x over previous
//
#include <hip/hip_runtime.h>
#include <math.h>

#define B_    32
#define T_    512
#define WDIM_ 300
#define H_    256
#define G4_   1024            // 4*H
#define M_    (B_ * T_)       // 16384

// persistent-LSTM geometry: team = 8 WGs covering one (dir, batch-pair)
#define NCG   8               // col groups per team (32 d's each)
#define NWG   256             // 2 dirs * 16 batch-pairs * NCG
#define THR   512
#define HXN   (2 * 2 * B_ * H_)   // packets: [buf][dir][32][256]

// ---------------------------------------------------------------------------
// Kernel 1: z = relu(emb[x] @ W_in + b_in)   [16384,300]@[300,256]
// ---------------------------------------------------------------------------
__global__ __launch_bounds__(256)
void k_embed_proj(const float* __restrict__ emb, const float* __restrict__ Win,
                  const float* __restrict__ bin, const int* __restrict__ x,
                  float* __restrict__ z)
{
    __shared__ float Ash[16][132];
    __shared__ float Bsh[16][132];
    __shared__ int   rows[128];

    const int tid = threadIdx.x;
    const int tx = tid & 15, ty = tid >> 4;
    const int rm = blockIdx.y * 128;
    const int cn = blockIdx.x * 128;

    if (tid < 128) rows[tid] = x[rm + tid];
    __syncthreads();

    float acc[8][8];
#pragma unroll
    for (int i = 0; i < 8; ++i)
#pragma unroll
        for (int j = 0; j < 8; ++j) acc[i][j] = 0.f;

    for (int kc = 0; kc < 19; ++kc) {
        const int k0 = kc * 16;
#pragma unroll
        for (int e = 0; e < 8; ++e) {
            const int idx = e * 256 + tid;
            const int r = idx >> 4, kk = idx & 15;
            const int k = k0 + kk;
            const int v = rows[r];
            Ash[kk][r] = (k < WDIM_) ? emb[(size_t)v * WDIM_ + k] : 0.f;
        }
#pragma unroll
        for (int e = 0; e < 8; ++e) {
            const int idx = e * 256 + tid;
            const int kk = idx >> 7, n = idx & 127;
            const int k = k0 + kk;
            Bsh[kk][n] = (k < WDIM_) ? Win[(size_t)k * H_ + cn + n] : 0.f;
        }
        __syncthreads();
#pragma unroll
        for (int kk = 0; kk < 16; ++kk) {
            float a[8], bb[8];
#pragma unroll
            for (int i = 0; i < 8; ++i) a[i] = Ash[kk][ty * 8 + i];
#pragma unroll
            for (int j = 0; j < 8; ++j) bb[j] = Bsh[kk][tx * 8 + j];
#pragma unroll
            for (int i = 0; i < 8; ++i)
#pragma unroll
                for (int j = 0; j < 8; ++j) acc[i][j] += a[i] * bb[j];
        }
        __syncthreads();
    }

#pragma unroll
    for (int i = 0; i < 8; ++i) {
        const int row = rm + ty * 8 + i;
#pragma unroll
        for (int j = 0; j < 8; ++j) {
            const int col = cn + tx * 8 + j;
            z[(size_t)row * H_ + col] = fmaxf(acc[i][j] + bin[col], 0.f);
        }
    }
}

// ---------------------------------------------------------------------------
// Kernel 2: P_d = z @ Wih_d + bl_d  (both directions via blockIdx.z)
// ---------------------------------------------------------------------------
__global__ __launch_bounds__(256)
void k_in_proj(const float* __restrict__ z,
               const float* __restrict__ Wf, const float* __restrict__ blf,
               const float* __restrict__ Wb, const float* __restrict__ blb,
               float* __restrict__ Pf, float* __restrict__ Pb)
{
    const float* W  = blockIdx.z ? Wb  : Wf;
    const float* bl = blockIdx.z ? blb : blf;
    float*       P  = blockIdx.z ? Pb  : Pf;

    __shared__ float Ash[16][132];
    __shared__ float Bsh[16][132];

    const int tid = threadIdx.x;
    const int tx = tid & 15, ty = tid >> 4;
    const int rm = blockIdx.y * 128;
    const int cn = blockIdx.x * 128;

    float acc[8][8];
#pragma unroll
    for (int i = 0; i < 8; ++i)
#pragma unroll
        for (int j = 0; j < 8; ++j) acc[i][j] = 0.f;

    for (int kc = 0; kc < 16; ++kc) {
        const int k0 = kc * 16;
#pragma unroll
        for (int e = 0; e < 8; ++e) {
            const int idx = e * 256 + tid;
            const int r = idx >> 4, kk = idx & 15;
            Ash[kk][r] = z[(size_t)(rm + r) * H_ + k0 + kk];
        }
#pragma unroll
        for (int e = 0; e < 8; ++e) {
            const int idx = e * 256 + tid;
            const int kk = idx >> 7, n = idx & 127;
            Bsh[kk][n] = W[(size_t)(k0 + kk) * G4_ + cn + n];
        }
        __syncthreads();
#pragma unroll
        for (int kk = 0; kk < 16; ++kk) {
            float a[8], bb[8];
#pragma unroll
            for (int i = 0; i < 8; ++i) a[i] = Ash[kk][ty * 8 + i];
#pragma unroll
            for (int j = 0; j < 8; ++j) bb[j] = Bsh[kk][tx * 8 + j];
#pragma unroll
            for (int i = 0; i < 8; ++i)
#pragma unroll
                for (int j = 0; j < 8; ++j) acc[i][j] += a[i] * bb[j];
        }
        __syncthreads();
    }

#pragma unroll
    for (int i = 0; i < 8; ++i) {
        const int row = rm + ty * 8 + i;
#pragma unroll
        for (int j = 0; j < 8; ++j) {
            const int col = cn + tx * 8 + j;
            P[(size_t)row * G4_ + col] = acc[i][j] + bl[col];
        }
    }
}

// ---------------------------------------------------------------------------
// Init: zero h packet buffers ({h=0, tag=0} == initial state)
// ---------------------------------------------------------------------------
__global__ void k_init(unsigned long long* __restrict__ hx)
{
    const int i = blockIdx.x * blockDim.x + threadIdx.x;
    if (i < HXN) hx[i] = 0ull;
}

// ---------------------------------------------------------------------------
// Kernel 3: persistent bidirectional LSTM recurrence, fence-free.
// WG = (dir, batch-pair bg, colgroup cg of 32 d's). Team = 8 colgroups.
// h published as {h,tag} 8-byte relaxed agent-scope atomic packets, double-
// buffered by step parity; readers poll tag>=s.
//
// v8: Whh slice stashed in ARCHITECTED AGPRS a0..a63 via explicit inline-asm
// v_accvgpr_write_b32 (prologue) / v_accvgpr_read_b32 (per step, volatile).
// History: the allocator spills any source-level 64-float slice to scratch
// (v1/v3/v5: VGPR_Count 56, ~2300cy/step L2 refetch); LDS delivery is
// DS-issue-bound (v7: ~800 DS instr/CU/step on the shared per-CU LDS pipe,
// 1130us, conflicts 0 -- conflicts were NOT the cost, instruction count
// was). Fixed AGPR numbers give regalloc no discretion: no remat, no
// scratch, no memory traffic. Cost: 64 VALU reads/thread/step (~+256
// cy/SIMD), removing ~2275 cy/step of L2 weight traffic.
// Budget: 64 AGPR + ~90 VGPR < 256/wave at 2 waves/SIMD -> occupancy kept.
// Everything else bitwise-identical to the 913us v1 (same GEMV order, same
// packet protocol, LDS back to 6144B).
// ---------------------------------------------------------------------------
__global__ __launch_bounds__(THR, 2)
void k_lstm_persist(const float* __restrict__ Pf, const float* __restrict__ Pb,
                    const float* __restrict__ Whf, const float* __restrict__ Whb,
                    const int* __restrict__ lengths,
                    unsigned long long* __restrict__ hx,
                    float* __restrict__ pool)
{
    __shared__ float h_sh[2][256];
    __shared__ float zp[4][2][128];   // [ksplit][row][local gate-col]

    const int tid = threadIdx.x;
    const int wg  = blockIdx.x;
    const int bg  = wg & 15;
    const int dir = (wg >> 4) & 1;
    const int cg  = wg >> 5;          // 0..7

    const float* P   = dir ? Pb  : Pf;
    const float* Whh = dir ? Whb : Whf;

    const int brow0 = bg * 2;
    const int len0 = lengths[brow0], len1 = lengths[brow0 + 1];
    const int tmax = max(len0, len1);

    // GEMV mapping: q = k-quarter, cl = local col in [0,128)
    const int q   = tid >> 7;
    const int cl  = tid & 127;
    const int g0  = cl >> 5;
    const int dd0 = cl & 31;
    const int gcol = g0 * 256 + cg * 32 + dd0;    // global column
    const int q64 = q * 64;

    // ---- prologue: stash the 64-float Whh slice into AGPRs a0..a63.
    // Explicit register numbers -> the allocator cannot spill or remat.
    {
        const float* wp = Whh + (size_t)q64 * G4_ + gcol;
#define STASH(K, AR) { const float twv = wp[(size_t)(K) * G4_]; \
        asm volatile("v_accvgpr_write_b32 " AR ", %0" :: "v"(twv) : AR); }
        STASH(0,"a0")   STASH(1,"a1")   STASH(2,"a2")   STASH(3,"a3")
        STASH(4,"a4")   STASH(5,"a5")   STASH(6,"a6")   STASH(7,"a7")
        STASH(8,"a8")   STASH(9,"a9")   STASH(10,"a10") STASH(11,"a11")
        STASH(12,"a12") STASH(13,"a13") STASH(14,"a14") STASH(15,"a15")
        STASH(16,"a16") STASH(17,"a17") STASH(18,"a18") STASH(19,"a19")
        STASH(20,"a20") STASH(21,"a21") STASH(22,"a22") STASH(23,"a23")
        STASH(24,"a24") STASH(25,"a25") STASH(26,"a26") STASH(27,"a27")
        STASH(28,"a28") STASH(29,"a29") STASH(30,"a30") STASH(31,"a31")
        STASH(32,"a32") STASH(33,"a33") STASH(34,"a34") STASH(35,"a35")
        STASH(36,"a36") STASH(37,"a37") STASH(38,"a38") STASH(39,"a39")
        STASH(40,"a40") STASH(41,"a41") STASH(42,"a42") STASH(43,"a43")
        STASH(44,"a44") STASH(45,"a45") STASH(46,"a46") STASH(47,"a47")
        STASH(48,"a48") STASH(49,"a49") STASH(50,"a50") STASH(51,"a51")
        STASH(52,"a52") STASH(53,"a53") STASH(54,"a54") STASH(55,"a55")
        STASH(56,"a56") STASH(57,"a57") STASH(58,"a58") STASH(59,"a59")
        STASH(60,"a60") STASH(61,"a61") STASH(62,"a62") STASH(63,"a63")
#undef STASH
    }

    // gate mapping (tid < 64): row gr, local hidden index gd
    const int gr    = tid >> 5;
    const int gd    = tid & 31;
    const int gbrow = brow0 + gr;
    const int glen  = gr ? len1 : len0;
    float cst = 0.f, hreg = 0.f, pacc = 0.f;

    // h-packet loader mapping (all 512 threads): row lrow, index ld
    const int lrow = tid >> 8;
    const int ld   = tid & 255;
    unsigned long long* slotR = hx + ((size_t)dir * 32 + brow0 + lrow) * 256 + ld;
    unsigned long long* slotW = hx + ((size_t)dir * 32 + gbrow) * 256 + cg * 32 + gd;
    const size_t bufStride = (size_t)2 * B_ * H_;   // packets per parity

    for (int s = 0; s < tmax; ++s) {
        const int tt = dir ? (tmax - 1 - s) : s;

        // prefetch input projection for this step (independent of the poll)
        float pv0 = 0.f, pv1 = 0.f, pv2 = 0.f, pv3 = 0.f;
        if (tid < 64) {
            const float* pr = P + (size_t)(gbrow * T_ + tt) * G4_ + cg * 32 + gd;
            pv0 = pr[0]; pv1 = pr[256]; pv2 = pr[512]; pv3 = pr[768];
        }

        // poll h_{s-1} packets (tag s) and stage into LDS
        {
            const unsigned long long* sp = slotR + (size_t)(s & 1) * bufStride;
            unsigned long long pk = __hip_atomic_load(sp, __ATOMIC_RELAXED,
                                                      __HIP_MEMORY_SCOPE_AGENT);
            while ((unsigned)(pk >> 32) < (unsigned)s) {
                __builtin_amdgcn_s_sleep(1);
                pk = __hip_atomic_load(sp, __ATOMIC_RELAXED,
                                       __HIP_MEMORY_SCOPE_AGENT);
            }
            h_sh[lrow][ld] = __uint_as_float((unsigned)pk);
        }
        __syncthreads();

        // GEMV: 2 rows x 1 col over k in [64q, 64q+64); weights from AGPRs
        {
            const float* h0 = &h_sh[0][q64];
            const float* h1 = &h_sh[1][q64];
            float a0 = 0.f, a1 = 0.f;
#define GQ(J, A0, A1, A2, A3) { \
            float wa, wb, wc, wd; \
            asm volatile("v_accvgpr_read_b32 %0, " A0 : "=v"(wa)); \
            asm volatile("v_accvgpr_read_b32 %0, " A1 : "=v"(wb)); \
            asm volatile("v_accvgpr_read_b32 %0, " A2 : "=v"(wc)); \
            asm volatile("v_accvgpr_read_b32 %0, " A3 : "=v"(wd)); \
            const float4 hv0 = *(const float4*)(h0 + 4 * (J)); \
            const float4 hv1 = *(const float4*)(h1 + 4 * (J)); \
            a0 += hv0.x * wa; a1 += hv1.x * wa; \
            a0 += hv0.y * wb; a1 += hv1.y * wb; \
            a0 += hv0.z * wc; a1 += hv1.z * wc; \
            a0 += hv0.w * wd; a1 += hv1.w * wd; }
            GQ(0,  "a0",  "a1",  "a2",  "a3")
            GQ(1,  "a4",  "a5",  "a6",  "a7")
            GQ(2,  "a8",  "a9",  "a10", "a11")
            GQ(3,  "a12", "a13", "a14", "a15")
            GQ(4,  "a16", "a17", "a18", "a19")
            GQ(5,  "a20", "a21", "a22", "a23")
            GQ(6,  "a24", "a25", "a26", "a27")
            GQ(7,  "a28", "a29", "a30", "a31")
            GQ(8,  "a32", "a33", "a34", "a35")
            GQ(9,  "a36", "a37", "a38", "a39")
            GQ(10, "a40", "a41", "a42", "a43")
            GQ(11, "a44", "a45", "a46", "a47")
            GQ(12, "a48", "a49", "a50", "a51")
            GQ(13, "a52", "a53", "a54", "a55")
            GQ(14, "a56", "a57", "a58", "a59")
            GQ(15, "a60", "a61", "a62", "a63")
#undef GQ
            zp[q][0][cl] = a0;
            zp[q][1][cl] = a1;
        }
        __syncthreads();

        // gates + state update + h-packet publish (tag s+1, parity (s+1)&1)
        if (tid < 64) {
            float zi = pv0 + zp[0][gr][gd]      + zp[1][gr][gd]      + zp[2][gr][gd]      + zp[3][gr][gd];
            float zf = pv1 + zp[0][gr][32 + gd] + zp[1][gr][32 + gd] + zp[2][gr][32 + gd] + zp[3][gr][32 + gd];
            float zg = pv2 + zp[0][gr][64 + gd] + zp[1][gr][64 + gd] + zp[2][gr][64 + gd] + zp[3][gr][64 + gd];
            float zo = pv3 + zp[0][gr][96 + gd] + zp[1][gr][96 + gd] + zp[2][gr][96 + gd] + zp[3][gr][96 + gd];
            const float ig = 1.f / (1.f + expf(-zi));
            const float fg = 1.f / (1.f + expf(-zf));
            const float gg = tanhf(zg);
            const float og = 1.f / (1.f + expf(-zo));
            const float cn = fg * cst + ig * gg;
            const float hn = og * tanhf(cn);
            if (tt < glen) { cst = cn; hreg = hn; pacc += hn; }
            const unsigned long long opk =
                ((unsigned long long)(unsigned)(s + 1) << 32) |
                (unsigned long long)__float_as_uint(hreg);
            __hip_atomic_store(slotW + (size_t)((s + 1) & 1) * bufStride, opk,
                               __ATOMIC_RELAXED, __HIP_MEMORY_SCOPE_AGENT);
        }
        // no trailing barrier: zp of step s+1 is written only after the next
        // post-poll __syncthreads, which gate threads reach after this block.
    }

    if (tid < 64)
        pool[gbrow * 512 + dir * 256 + cg * 32 + gd] = pacc / (float)glen;
}

// ---------------------------------------------------------------------------
// Kernel 4: fc_hidden = relu(pool @ Wfc + bfc); out = fc_hidden @ Wout + bout
// ---------------------------------------------------------------------------
__global__ __launch_bounds__(256)
void k_fc(const float* __restrict__ pool, const float* __restrict__ Wfc,
          const float* __restrict__ bfc, const float* __restrict__ Wout,
          const float* __restrict__ bout, float* __restrict__ out)
{
    __shared__ float p_sh[512];
    __shared__ float red[8];

    const int tid = threadIdx.x;
    const int b   = blockIdx.x;

    p_sh[tid]       = pool[b * 512 + tid];
    p_sh[256 + tid] = pool[b * 512 + 256 + tid];
    __syncthreads();

    float acc = bfc[tid];
#pragma unroll 8
    for (int k = 0; k < 512; ++k)
        acc += p_sh[k] * Wfc[(size_t)k * H_ + tid];
    const float fh = fmaxf(acc, 0.f);

    float p0 = fh * Wout[tid * 2 + 0];
    float p1 = fh * Wout[tid * 2 + 1];
#pragma unroll
    for (int off = 32; off > 0; off >>= 1) {
        p0 += __shfl_down(p0, off);
        p1 += __shfl_down(p1, off);
    }
    const int wave = tid >> 6;
    if ((tid & 63) == 0) { red[wave * 2] = p0; red[wave * 2 + 1] = p1; }
    __syncthreads();
    if (tid == 0) {
        out[b * 2 + 0] = red[0] + red[2] + red[4] + red[6] + bout[0];
        out[b * 2 + 1] = red[1] + red[3] + red[5] + red[7] + bout[1];
    }
}

__global__ void k_sentinel(float* out, int n)
{
    const int i = blockIdx.x * blockDim.x + threadIdx.x;
    if (i < n) out[i] = 1.0e9f;
}

extern "C" void kernel_launch(void* const* d_in, const int* in_sizes, int n_in,
                              void* d_out, int out_size, void* d_ws, size_t ws_size,
                              hipStream_t stream)
{
    const float* emb  = (const float*)d_in[0];
    const float* Win  = (const float*)d_in[1];
    const float* bin  = (const float*)d_in[2];
    const float* Wihf = (const float*)d_in[3];
    const float* Whhf = (const float*)d_in[4];
    const float* blf  = (const float*)d_in[5];
    const float* Wihb = (const float*)d_in[6];
    const float* Whhb = (const float*)d_in[7];
    const float* blb  = (const float*)d_in[8];
    const float* Wfc  = (const float*)d_in[9];
    const float* bfc  = (const float*)d_in[10];
    const float* Wout = (const float*)d_in[11];
    const float* bout = (const float*)d_in[12];
    const int*   x    = (const int*)d_in[13];
    const int*   lens = (const int*)d_in[15];
    float*       out  = (float*)d_out;

    const size_t need = ((size_t)M_ * H_ + 2 * (size_t)M_ * G4_) * sizeof(float);
    if (ws_size < need) {
        hipLaunchKernelGGL(k_sentinel, dim3(1), dim3(64), 0, stream, out, out_size);
        return;
    }

    float* z  = (float*)d_ws;                    // [16384,256] (dead after k2)
    float* Pf = z + (size_t)M_ * H_;             // [16384,1024]
    float* Pb = Pf + (size_t)M_ * G4_;           // [16384,1024]

    // overlay inside z region (init runs after k2 has consumed z)
    unsigned long long* hx   = (unsigned long long*)d_ws;        // packets
    float*              pool = (float*)(hx + HXN);               // [32][512]

    hipLaunchKernelGGL(k_embed_proj, dim3(2, 128), dim3(256), 0, stream,
                       emb, Win, bin, x, z);
    hipLaunchKernelGGL(k_in_proj, dim3(8, 128, 2), dim3(256), 0, stream,
                       z, Wihf, blf, Wihb, blb, Pf, Pb);
    hipLaunchKernelGGL(k_init, dim3(128), dim3(256), 0, stream, hx);
    hipLaunchKernelGGL(k_lstm_persist, dim3(NWG), dim3(THR), 0, stream,
                       Pf, Pb, Whhf, Whhb, lens, hx, pool);
    hipLaunchKernelGGL(k_fc, dim3(32), dim3(256), 0, stream,
                       pool, Wfc, bfc, Wout, bout, out);
}

// Round 9
// 1463.439 us; speedup vs baseline: 1.0862x; 1.0159x over previous
//
#include <hip/hip_runtime.h>
#include <math.h>

#define B_    32
#define T_    512
#define WDIM_ 300
#define H_    256
#define G4_   1024            // 4*H
#define M_    (B_ * T_)       // 16384

// persistent-LSTM geometry: team = 8 WGs covering one (dir, batch-pair)
#define NCG   8               // col groups per team (32 d's each)
#define NWG   256             // 2 dirs * 16 batch-pairs * NCG
#define THR   512
#define HXN   (2 * 2 * B_ * H_)   // packets: [buf][dir][32][256]

// ---------------------------------------------------------------------------
// Kernel 1: z = relu(emb[x] @ W_in + b_in)   [16384,300]@[300,256]
// ---------------------------------------------------------------------------
__global__ __launch_bounds__(256)
void k_embed_proj(const float* __restrict__ emb, const float* __restrict__ Win,
                  const float* __restrict__ bin, const int* __restrict__ x,
                  float* __restrict__ z)
{
    __shared__ float Ash[16][132];
    __shared__ float Bsh[16][132];
    __shared__ int   rows[128];

    const int tid = threadIdx.x;
    const int tx = tid & 15, ty = tid >> 4;
    const int rm = blockIdx.y * 128;
    const int cn = blockIdx.x * 128;

    if (tid < 128) rows[tid] = x[rm + tid];
    __syncthreads();

    float acc[8][8];
#pragma unroll
    for (int i = 0; i < 8; ++i)
#pragma unroll
        for (int j = 0; j < 8; ++j) acc[i][j] = 0.f;

    for (int kc = 0; kc < 19; ++kc) {
        const int k0 = kc * 16;
#pragma unroll
        for (int e = 0; e < 8; ++e) {
            const int idx = e * 256 + tid;
            const int r = idx >> 4, kk = idx & 15;
            const int k = k0 + kk;
            const int v = rows[r];
            Ash[kk][r] = (k < WDIM_) ? emb[(size_t)v * WDIM_ + k] : 0.f;
        }
#pragma unroll
        for (int e = 0; e < 8; ++e) {
            const int idx = e * 256 + tid;
            const int kk = idx >> 7, n = idx & 127;
            const int k = k0 + kk;
            Bsh[kk][n] = (k < WDIM_) ? Win[(size_t)k * H_ + cn + n] : 0.f;
        }
        __syncthreads();
#pragma unroll
        for (int kk = 0; kk < 16; ++kk) {
            float a[8], bb[8];
#pragma unroll
            for (int i = 0; i < 8; ++i) a[i] = Ash[kk][ty * 8 + i];
#pragma unroll
            for (int j = 0; j < 8; ++j) bb[j] = Bsh[kk][tx * 8 + j];
#pragma unroll
            for (int i = 0; i < 8; ++i)
#pragma unroll
                for (int j = 0; j < 8; ++j) acc[i][j] += a[i] * bb[j];
        }
        __syncthreads();
    }

#pragma unroll
    for (int i = 0; i < 8; ++i) {
        const int row = rm + ty * 8 + i;
#pragma unroll
        for (int j = 0; j < 8; ++j) {
            const int col = cn + tx * 8 + j;
            z[(size_t)row * H_ + col] = fmaxf(acc[i][j] + bin[col], 0.f);
        }
    }
}

// ---------------------------------------------------------------------------
// Kernel 2: P_d = z @ Wih_d + bl_d  (both directions via blockIdx.z)
// ---------------------------------------------------------------------------
__global__ __launch_bounds__(256)
void k_in_proj(const float* __restrict__ z,
               const float* __restrict__ Wf, const float* __restrict__ blf,
               const float* __restrict__ Wb, const float* __restrict__ blb,
               float* __restrict__ Pf, float* __restrict__ Pb)
{
    const float* W  = blockIdx.z ? Wb  : Wf;
    const float* bl = blockIdx.z ? blb : blf;
    float*       P  = blockIdx.z ? Pb  : Pf;

    __shared__ float Ash[16][132];
    __shared__ float Bsh[16][132];

    const int tid = threadIdx.x;
    const int tx = tid & 15, ty = tid >> 4;
    const int rm = blockIdx.y * 128;
    const int cn = blockIdx.x * 128;

    float acc[8][8];
#pragma unroll
    for (int i = 0; i < 8; ++i)
#pragma unroll
        for (int j = 0; j < 8; ++j) acc[i][j] = 0.f;

    for (int kc = 0; kc < 16; ++kc) {
        const int k0 = kc * 16;
#pragma unroll
        for (int e = 0; e < 8; ++e) {
            const int idx = e * 256 + tid;
            const int r = idx >> 4, kk = idx & 15;
            Ash[kk][r] = z[(size_t)(rm + r) * H_ + k0 + kk];
        }
#pragma unroll
        for (int e = 0; e < 8; ++e) {
            const int idx = e * 256 + tid;
            const int kk = idx >> 7, n = idx & 127;
            Bsh[kk][n] = W[(size_t)(k0 + kk) * G4_ + cn + n];
        }
        __syncthreads();
#pragma unroll
        for (int kk = 0; kk < 16; ++kk) {
            float a[8], bb[8];
#pragma unroll
            for (int i = 0; i < 8; ++i) a[i] = Ash[kk][ty * 8 + i];
#pragma unroll
            for (int j = 0; j < 8; ++j) bb[j] = Bsh[kk][tx * 8 + j];
#pragma unroll
            for (int i = 0; i < 8; ++i)
#pragma unroll
                for (int j = 0; j < 8; ++j) acc[i][j] += a[i] * bb[j];
        }
        __syncthreads();
    }

#pragma unroll
    for (int i = 0; i < 8; ++i) {
        const int row = rm + ty * 8 + i;
#pragma unroll
        for (int j = 0; j < 8; ++j) {
            const int col = cn + tx * 8 + j;
            P[(size_t)row * G4_ + col] = acc[i][j] + bl[col];
        }
    }
}

// ---------------------------------------------------------------------------
// Init: zero h packet buffers ({h=0, tag=0} == initial state) AND compute
// the length-sorted row permutation: perm[rank] = row, ranked by descending
// length. Pairing adjacent ranks minimizes sum of per-pair max(len) --
// E[sum max] drops ~9% vs index-order pairing. Row arithmetic is partner-
// independent, so results are bitwise unchanged.
// ---------------------------------------------------------------------------
__global__ void k_init(unsigned long long* __restrict__ hx,
                       const int* __restrict__ lengths,
                       int* __restrict__ perm)
{
    const int i = blockIdx.x * blockDim.x + threadIdx.x;
    if (i < HXN) hx[i] = 0ull;
    if (blockIdx.x == 0 && threadIdx.x < B_) {
        const int li = lengths[threadIdx.x];
        int rank = 0;
        for (int j = 0; j < B_; ++j) {
            const int lj = lengths[j];
            if (lj > li || (lj == li && j < (int)threadIdx.x)) ++rank;
        }
        perm[rank] = threadIdx.x;
    }
}

// ---------------------------------------------------------------------------
// Kernel 3: persistent bidirectional LSTM recurrence, fence-free.
// WG = (dir, batch-pair bg, colgroup cg of 32 d's). Team = 8 colgroups.
// h published as {h,tag} 8-byte relaxed agent-scope atomic packets, double-
// buffered by step parity; readers poll tag>=s.
//
// v9 = v1 (913us, the best structure: delivery experiments v6-v8 proved
// weight delivery is OFF the critical path -- scratch reloads drain during
// the poll stall) + three chain/step-count optimizations:
//  (1) length-sorted pairing via perm[]: pairs have similar lengths ->
//      sum over pairs of max(len) drops ~9% (fewer recurrence steps).
//  (2) poll loop drops s_sleep(1): the 64-cyc sleep quantum added to
//      detection latency every miss; vmcnt stalls already yield the SIMD.
//  (3) self-packets skip L2: the WG's own 64 h values (its cg dims) are
//      written to h_sh directly by the gate wave; only 192 remote packets
//      are polled. Own-value L2 round trip removed.
// Per-row arithmetic is bitwise-identical to v1 (absmax stays 0).
// ---------------------------------------------------------------------------
__global__ __launch_bounds__(THR, 2)
void k_lstm_persist(const float* __restrict__ Pf, const float* __restrict__ Pb,
                    const float* __restrict__ Whf, const float* __restrict__ Whb,
                    const int* __restrict__ lengths,
                    const int* __restrict__ perm,
                    unsigned long long* __restrict__ hx,
                    float* __restrict__ pool)
{
    __shared__ float h_sh[2][256];
    __shared__ float zp[4][2][128];   // [ksplit][row][local gate-col]

    const int tid = threadIdx.x;
    const int wg  = blockIdx.x;
    const int bg  = wg & 15;
    const int dir = (wg >> 4) & 1;
    const int cg  = wg >> 5;          // 0..7

    const float* P   = dir ? Pb  : Pf;
    const float* Whh = dir ? Whb : Whf;

    const int row0 = perm[bg * 2];
    const int row1 = perm[bg * 2 + 1];
    const int len0 = lengths[row0], len1 = lengths[row1];
    const int tmax = max(len0, len1);

    // GEMV mapping: q = k-quarter, cl = local col in [0,128)
    const int q   = tid >> 7;
    const int cl  = tid & 127;
    const int g0  = cl >> 5;
    const int dd0 = cl & 31;
    const int gcol = g0 * 256 + cg * 32 + dd0;    // global column
    const int q64 = q * 64;

    // persistent W slice: 64 floats (compiler scratches it; reloads are
    // dependence-free and drain during the poll stall -- proven v6/v7/v8)
    float wv[64];
    {
        const float* wp = Whh + (size_t)q64 * G4_ + gcol;
#pragma unroll
        for (int k = 0; k < 64; ++k) wv[k] = wp[(size_t)k * G4_];
    }

    // gate mapping (tid < 64): row gr, local hidden index gd
    const int gr    = tid >> 5;
    const int gd    = tid & 31;
    const int gbrow = gr ? row1 : row0;
    const int glen  = gr ? len1 : len0;
    float cst = 0.f, hreg = 0.f, pacc = 0.f;

    // h-packet loader mapping (all 512 threads): row lrow, index ld
    const int lrow = tid >> 8;
    const int ld   = tid & 255;
    const int rrow = lrow ? row1 : row0;
    const bool selfpk = (ld >> 5) == cg;      // own-cg dims: no L2 poll
    unsigned long long* slotR = hx + ((size_t)dir * 32 + rrow) * 256 + ld;
    unsigned long long* slotW = hx + ((size_t)dir * 32 + gbrow) * 256 + cg * 32 + gd;
    const size_t bufStride = (size_t)2 * B_ * H_;   // packets per parity

    // initial state: all h = 0 (self-skipped slots must start zeroed)
    h_sh[lrow][ld] = 0.f;

    for (int s = 0; s < tmax; ++s) {
        const int tt = dir ? (tmax - 1 - s) : s;

        // prefetch input projection for this step (independent of the poll)
        float pv0 = 0.f, pv1 = 0.f, pv2 = 0.f, pv3 = 0.f;
        if (tid < 64) {
            const float* pr = P + (size_t)(gbrow * T_ + tt) * G4_ + cg * 32 + gd;
            pv0 = pr[0]; pv1 = pr[256]; pv2 = pr[512]; pv3 = pr[768];
        }

        // poll remote h_{s-1} packets (tag s) and stage into LDS
        if (!selfpk) {
            const unsigned long long* sp = slotR + (size_t)(s & 1) * bufStride;
            unsigned long long pk = __hip_atomic_load(sp, __ATOMIC_RELAXED,
                                                      __HIP_MEMORY_SCOPE_AGENT);
            while ((unsigned)(pk >> 32) < (unsigned)s) {
                pk = __hip_atomic_load(sp, __ATOMIC_RELAXED,
                                       __HIP_MEMORY_SCOPE_AGENT);
            }
            h_sh[lrow][ld] = __uint_as_float((unsigned)pk);
        }
        __syncthreads();

        // GEMV: 2 rows x 1 col over k in [64q, 64q+64)
        {
            const float* h0 = &h_sh[0][q64];
            const float* h1 = &h_sh[1][q64];
            float a0 = 0.f, a1 = 0.f;
#pragma unroll
            for (int j4 = 0; j4 < 16; ++j4) {
                const float4 hv0 = *(const float4*)(h0 + 4 * j4);
                const float4 hv1 = *(const float4*)(h1 + 4 * j4);
                a0 += hv0.x * wv[4*j4  ]; a1 += hv1.x * wv[4*j4  ];
                a0 += hv0.y * wv[4*j4+1]; a1 += hv1.y * wv[4*j4+1];
                a0 += hv0.z * wv[4*j4+2]; a1 += hv1.z * wv[4*j4+2];
                a0 += hv0.w * wv[4*j4+3]; a1 += hv1.w * wv[4*j4+3];
            }
            zp[q][0][cl] = a0;
            zp[q][1][cl] = a1;
        }
        __syncthreads();

        // gates + state update + h publish (LDS for self, L2 for remote)
        if (tid < 64) {
            float zi = pv0 + zp[0][gr][gd]      + zp[1][gr][gd]      + zp[2][gr][gd]      + zp[3][gr][gd];
            float zf = pv1 + zp[0][gr][32 + gd] + zp[1][gr][32 + gd] + zp[2][gr][32 + gd] + zp[3][gr][32 + gd];
            float zg = pv2 + zp[0][gr][64 + gd] + zp[1][gr][64 + gd] + zp[2][gr][64 + gd] + zp[3][gr][64 + gd];
            float zo = pv3 + zp[0][gr][96 + gd] + zp[1][gr][96 + gd] + zp[2][gr][96 + gd] + zp[3][gr][96 + gd];
            const float ig = 1.f / (1.f + expf(-zi));
            const float fg = 1.f / (1.f + expf(-zf));
            const float gg = tanhf(zg);
            const float og = 1.f / (1.f + expf(-zo));
            const float cn = fg * cst + ig * gg;
            const float hn = og * tanhf(cn);
            if (tt < glen) { cst = cn; hreg = hn; pacc += hn; }
            // self-publish via LDS (consumed after next barrier)
            h_sh[gr][cg * 32 + gd] = hreg;
            const unsigned long long opk =
                ((unsigned long long)(unsigned)(s + 1) << 32) |
                (unsigned long long)__float_as_uint(hreg);
            __hip_atomic_store(slotW + (size_t)((s + 1) & 1) * bufStride, opk,
                               __ATOMIC_RELAXED, __HIP_MEMORY_SCOPE_AGENT);
        }
        // no trailing barrier: zp of step s+1 is written only after the next
        // post-poll __syncthreads, which gate threads reach after this block.
    }

    if (tid < 64)
        pool[gbrow * 512 + dir * 256 + cg * 32 + gd] = pacc / (float)glen;
}

// ---------------------------------------------------------------------------
// Kernel 4: fc_hidden = relu(pool @ Wfc + bfc); out = fc_hidden @ Wout + bout
// ---------------------------------------------------------------------------
__global__ __launch_bounds__(256)
void k_fc(const float* __restrict__ pool, const float* __restrict__ Wfc,
          const float* __restrict__ bfc, const float* __restrict__ Wout,
          const float* __restrict__ bout, float* __restrict__ out)
{
    __shared__ float p_sh[512];
    __shared__ float red[8];

    const int tid = threadIdx.x;
    const int b   = blockIdx.x;

    p_sh[tid]       = pool[b * 512 + tid];
    p_sh[256 + tid] = pool[b * 512 + 256 + tid];
    __syncthreads();

    float acc = bfc[tid];
#pragma unroll 8
    for (int k = 0; k < 512; ++k)
        acc += p_sh[k] * Wfc[(size_t)k * H_ + tid];
    const float fh = fmaxf(acc, 0.f);

    float p0 = fh * Wout[tid * 2 + 0];
    float p1 = fh * Wout[tid * 2 + 1];
#pragma unroll
    for (int off = 32; off > 0; off >>= 1) {
        p0 += __shfl_down(p0, off);
        p1 += __shfl_down(p1, off);
    }
    const int wave = tid >> 6;
    if ((tid & 63) == 0) { red[wave * 2] = p0; red[wave * 2 + 1] = p1; }
    __syncthreads();
    if (tid == 0) {
        out[b * 2 + 0] = red[0] + red[2] + red[4] + red[6] + bout[0];
        out[b * 2 + 1] = red[1] + red[3] + red[5] + red[7] + bout[1];
    }
}

__global__ void k_sentinel(float* out, int n)
{
    const int i = blockIdx.x * blockDim.x + threadIdx.x;
    if (i < n) out[i] = 1.0e9f;
}

extern "C" void kernel_launch(void* const* d_in, const int* in_sizes, int n_in,
                              void* d_out, int out_size, void* d_ws, size_t ws_size,
                              hipStream_t stream)
{
    const float* emb  = (const float*)d_in[0];
    const float* Win  = (const float*)d_in[1];
    const float* bin  = (const float*)d_in[2];
    const float* Wihf = (const float*)d_in[3];
    const float* Whhf = (const float*)d_in[4];
    const float* blf  = (const float*)d_in[5];
    const float* Wihb = (const float*)d_in[6];
    const float* Whhb = (const float*)d_in[7];
    const float* blb  = (const float*)d_in[8];
    const float* Wfc  = (const float*)d_in[9];
    const float* bfc  = (const float*)d_in[10];
    const float* Wout = (const float*)d_in[11];
    const float* bout = (const float*)d_in[12];
    const int*   x    = (const int*)d_in[13];
    const int*   lens = (const int*)d_in[15];
    float*       out  = (float*)d_out;

    const size_t need = ((size_t)M_ * H_ + 2 * (size_t)M_ * G4_) * sizeof(float);
    if (ws_size < need) {
        hipLaunchKernelGGL(k_sentinel, dim3(1), dim3(64), 0, stream, out, out_size);
        return;
    }

    float* z  = (float*)d_ws;                    // [16384,256] (dead after k2)
    float* Pf = z + (size_t)M_ * H_;             // [16384,1024]
    float* Pb = Pf + (size_t)M_ * G4_;           // [16384,1024]

    // overlay inside z region (init runs after k2 has consumed z)
    unsigned long long* hx   = (unsigned long long*)d_ws;        // packets
    float*              pool = (float*)(hx + HXN);               // [32][512]
    int*                perm = (int*)(pool + 32 * 512);          // [32]

    hipLaunchKernelGGL(k_embed_proj, dim3(2, 128), dim3(256), 0, stream,
                       emb, Win, bin, x, z);
    hipLaunchKernelGGL(k_in_proj, dim3(8, 128, 2), dim3(256), 0, stream,
                       z, Wihf, blf, Wihb, blb, Pf, Pb);
    hipLaunchKernelGGL(k_init, dim3(128), dim3(256), 0, stream, hx, lens, perm);
    hipLaunchKernelGGL(k_lstm_persist, dim3(NWG), dim3(THR), 0, stream,
                       Pf, Pb, Whhf, Whhb, lens, perm, hx, pool);
    hipLaunchKernelGGL(k_fc, dim3(32), dim3(256), 0, stream,
                       pool, Wfc, bfc, Wout, bout, out);
}